// Round 2
// baseline (628.409 us; speedup 1.0000x reference)
//
#include <hip/hip_runtime.h>
#include <hip/hip_bf16.h>

#define B_  512
#define D_  256
#define O_  256
#define H2_ 1024

typedef __attribute__((ext_vector_type(4))) float  f32x4;
typedef __attribute__((ext_vector_type(8))) short  short8;
typedef __attribute__((ext_vector_type(4))) short  short4v;

union S8u { short4v v; unsigned u[2]; };

// fp32 -> bf16 round-to-nearest-even on raw bits (finite inputs only)
__device__ __forceinline__ unsigned f32_bf16(float x) {
  unsigned u = __builtin_bit_cast(unsigned, x);
  return (u + 0x7fffu + ((u >> 16) & 1u)) >> 16;
}
__device__ __forceinline__ unsigned cvt_pk_bf16(float a, float b) {
  return f32_bf16(a) | (f32_bf16(b) << 16);
}

// ---------------------------------------------------------------------------
// Generic small GEMM: C[M,N] = act(A[M,K] @ B[N,K]^T + bias[N]); fp32 in/out,
// bf16 MFMA inside. 64x64 tile per block, 256 threads = 4 waves, each wave a
// 32x32 quadrant (2x2 of 16x16x32 mfma), BK=64. All dims multiples of 64.
// ---------------------------------------------------------------------------
template <int RELU>
__global__ __launch_bounds__(256)
void gemm_bt64(const float* __restrict__ A, const float* __restrict__ Bm,
               const float* __restrict__ bias, float* __restrict__ C,
               int M, int N, int K) {
  __shared__ __align__(16) short As[64][72];  // +8 pad: 144B rows, 2-way-free banks
  __shared__ __align__(16) short Bs[64][72];
  const int t    = threadIdx.x;
  const int m0   = blockIdx.y * 64;
  const int n0   = blockIdx.x * 64;
  const int f4c  = t & 15;   // float4 column within 64-wide K slice
  const int rg   = t >> 4;   // row group 0..15
  const int lane = t & 63;
  const int w    = t >> 6;
  const int wm   = (w & 1) * 32;
  const int wn   = (w >> 1) * 32;
  const int lr   = lane & 15;
  const int lq   = lane >> 4;

  f32x4 acc[2][2];
  #pragma unroll
  for (int i = 0; i < 2; ++i)
    #pragma unroll
    for (int j = 0; j < 2; ++j) acc[i][j] = f32x4{0.f, 0.f, 0.f, 0.f};

  for (int k0 = 0; k0 < K; k0 += 64) {
    #pragma unroll
    for (int j = 0; j < 4; ++j) {
      int r = rg + 16 * j;
      f32x4 av = *(const f32x4*)(A  + (size_t)(m0 + r) * K + k0 + f4c * 4);
      f32x4 bv = *(const f32x4*)(Bm + (size_t)(n0 + r) * K + k0 + f4c * 4);
      S8u sa; sa.u[0] = cvt_pk_bf16(av.x, av.y); sa.u[1] = cvt_pk_bf16(av.z, av.w);
      S8u sb; sb.u[0] = cvt_pk_bf16(bv.x, bv.y); sb.u[1] = cvt_pk_bf16(bv.z, bv.w);
      *(short4v*)&As[r][f4c * 4] = sa.v;
      *(short4v*)&Bs[r][f4c * 4] = sb.v;
    }
    __syncthreads();
    #pragma unroll
    for (int ks = 0; ks < 2; ++ks) {
      short8 a0 = *(const short8*)&As[wm + lr     ][ks * 32 + lq * 8];
      short8 a1 = *(const short8*)&As[wm + 16 + lr][ks * 32 + lq * 8];
      short8 b0 = *(const short8*)&Bs[wn + lr     ][ks * 32 + lq * 8];
      short8 b1 = *(const short8*)&Bs[wn + 16 + lr][ks * 32 + lq * 8];
      acc[0][0] = __builtin_amdgcn_mfma_f32_16x16x32_bf16(a0, b0, acc[0][0], 0, 0, 0);
      acc[0][1] = __builtin_amdgcn_mfma_f32_16x16x32_bf16(a0, b1, acc[0][1], 0, 0, 0);
      acc[1][0] = __builtin_amdgcn_mfma_f32_16x16x32_bf16(a1, b0, acc[1][0], 0, 0, 0);
      acc[1][1] = __builtin_amdgcn_mfma_f32_16x16x32_bf16(a1, b1, acc[1][1], 0, 0, 0);
    }
    __syncthreads();
  }
  // C/D layout (verified m89): col = lane&15, row = (lane>>4)*4 + reg
  #pragma unroll
  for (int mi = 0; mi < 2; ++mi)
    #pragma unroll
    for (int ni = 0; ni < 2; ++ni)
      #pragma unroll
      for (int r = 0; r < 4; ++r) {
        int row = m0 + wm + mi * 16 + lq * 4 + r;
        int col = n0 + wn + ni * 16 + lr;
        float v = acc[mi][ni][r] + bias[col];
        if (RELU) v = fmaxf(v, 0.f);
        C[(size_t)row * N + col] = v;
      }
}

// ---------------------------------------------------------------------------
// out[b,o] += sum_d input[b,d] * b_d[d*O+o]   (one block per b row)
// ---------------------------------------------------------------------------
__global__ __launch_bounds__(256)
void bias_d_kernel(const float* __restrict__ inp, const float* __restrict__ b_d,
                   float* __restrict__ out) {
  const int b = blockIdx.x;
  const int o = threadIdx.x;
  const float* ir = inp + (size_t)b * D_;
  float s = 0.f;
  for (int d = 0; d < D_; ++d)
    s += ir[d] * b_d[(size_t)d * O_ + o];  // coalesced over o, b_d L2-resident
  out[(size_t)b * O_ + o] += s;
}

// ---------------------------------------------------------------------------
// Stage B: out[b,o] += sum_{d,h} (input[b,d]*x2[b,h]) * W_d[(d*O+o), h]
// One fused GEMM M=512, N=256, K=262144. Per WG: 128x128 C tile, K-chunk of
// 4 d-blocks (4096 K). A synthesized = x2 row-scaled by input[:,d]. Split-K
// partials atomically added to out (pre-initialized with comp_b + bias_d).
// grid = (8 tiles fast-varying for W L3 sharing, 64 k-splits)
// ---------------------------------------------------------------------------
__global__ __launch_bounds__(256, 2)
void stage_b(const float* __restrict__ x2, const float* __restrict__ inp,
             const float* __restrict__ Wd, float* __restrict__ out) {
  __shared__ __align__(16) short As[128][72];
  __shared__ __align__(16) short Bs[128][72];
  const int t    = threadIdx.x;
  const int mt   = blockIdx.x >> 1;
  const int nt   = blockIdx.x & 1;
  const int d0   = blockIdx.y * 4;
  const int bm   = mt * 128;
  const int bn   = nt * 128;
  const int f4c  = t & 15;
  const int rg   = t >> 4;
  const int lane = t & 63;
  const int w    = t >> 6;
  const int wm   = (w & 1) * 64;
  const int wn   = (w >> 1) * 64;
  const int lr   = lane & 15;
  const int lq   = lane >> 4;

  f32x4 acc[4][4];
  #pragma unroll
  for (int mi = 0; mi < 4; ++mi)
    #pragma unroll
    for (int ni = 0; ni < 4; ++ni) acc[mi][ni] = f32x4{0.f, 0.f, 0.f, 0.f};

  for (int dl = 0; dl < 4; ++dl) {
    const int d = d0 + dl;
    float insc[8];
    #pragma unroll
    for (int j = 0; j < 8; ++j)
      insc[j] = inp[(size_t)(bm + rg + 16 * j) * D_ + d];  // L2-hit scalar loads
    const float* wbase = Wd + ((size_t)d * O_ + bn) * H2_;

    for (int h0 = 0; h0 < H2_; h0 += 64) {
      #pragma unroll
      for (int j = 0; j < 8; ++j) {
        int r = rg + 16 * j;
        f32x4 xv = *(const f32x4*)(x2 + (size_t)(bm + r) * H2_ + h0 + f4c * 4);
        float s = insc[j];
        S8u sa;
        sa.u[0] = cvt_pk_bf16(xv.x * s, xv.y * s);
        sa.u[1] = cvt_pk_bf16(xv.z * s, xv.w * s);
        *(short4v*)&As[r][f4c * 4] = sa.v;
        f32x4 wv = *(const f32x4*)(wbase + (size_t)r * H2_ + h0 + f4c * 4);
        S8u sb; sb.u[0] = cvt_pk_bf16(wv.x, wv.y); sb.u[1] = cvt_pk_bf16(wv.z, wv.w);
        *(short4v*)&Bs[r][f4c * 4] = sb.v;
      }
      __syncthreads();
      #pragma unroll
      for (int ks = 0; ks < 2; ++ks) {
        short8 af[4], bfr[4];
        #pragma unroll
        for (int mi = 0; mi < 4; ++mi)
          af[mi] = *(const short8*)&As[wm + mi * 16 + lr][ks * 32 + lq * 8];
        #pragma unroll
        for (int ni = 0; ni < 4; ++ni)
          bfr[ni] = *(const short8*)&Bs[wn + ni * 16 + lr][ks * 32 + lq * 8];
        #pragma unroll
        for (int mi = 0; mi < 4; ++mi)
          #pragma unroll
          for (int ni = 0; ni < 4; ++ni)
            acc[mi][ni] = __builtin_amdgcn_mfma_f32_16x16x32_bf16(af[mi], bfr[ni],
                                                                  acc[mi][ni], 0, 0, 0);
      }
      __syncthreads();
    }
  }

  #pragma unroll
  for (int mi = 0; mi < 4; ++mi)
    #pragma unroll
    for (int ni = 0; ni < 4; ++ni)
      #pragma unroll
      for (int r = 0; r < 4; ++r) {
        int row = bm + wm + mi * 16 + lq * 4 + r;
        int col = bn + wn + ni * 16 + lr;
        atomicAdd(out + (size_t)row * O_ + col, acc[mi][ni][r]);
      }
}

extern "C" void kernel_launch(void* const* d_in, const int* in_sizes, int n_in,
                              void* d_out, int out_size, void* d_ws, size_t ws_size,
                              hipStream_t stream) {
  const float* input = (const float*)d_in[0];   // [512,256]
  const float* nanf  = (const float*)d_in[1];   // [512,256]
  // d_in[2] = training scalar (ignored; inference path)
  const float* W_in  = (const float*)d_in[3];   // [512,256]
  const float* b_in  = (const float*)d_in[4];
  const float* W_h1  = (const float*)d_in[5];   // [1024,512]
  const float* b_h1  = (const float*)d_in[6];
  const float* W_h2  = (const float*)d_in[7];   // [1024,1024]
  const float* b_h2  = (const float*)d_in[8];
  const float* W_d   = (const float*)d_in[9];   // [65536,1024]
  const float* b_d   = (const float*)d_in[10];  // [65536]
  const float* W_b   = (const float*)d_in[11];  // [256,1024]
  const float* b_b   = (const float*)d_in[12];  // [256]
  float* out = (float*)d_out;                   // [512,256]

  float* x0 = (float*)d_ws;          // [512,512]  1 MB
  float* x1 = x0 + 512 * 512;        // [512,1024] 2 MB
  float* x2 = x1 + 512 * 1024;       // [512,1024] 2 MB   (needs ws >= 5 MB)

  // Stage A: MLP (~2 GFLOP total)
  gemm_bt64<1><<<dim3(512 / 64, 512 / 64), 256, 0, stream>>>(nanf, W_in, b_in, x0, 512, 512, 256);
  gemm_bt64<1><<<dim3(1024 / 64, 512 / 64), 256, 0, stream>>>(x0, W_h1, b_h1, x1, 512, 1024, 512);
  gemm_bt64<1><<<dim3(1024 / 64, 512 / 64), 256, 0, stream>>>(x1, W_h2, b_h2, x2, 512, 1024, 1024);
  // out = x2 @ W_b^T + b_b   (comp_b, overwrites poisoned d_out)
  gemm_bt64<0><<<dim3(256 / 64, 512 / 64), 256, 0, stream>>>(x2, W_b, b_b, out, 512, 256, 1024);
  // out += input @ reshape(b_d, [D,O])
  bias_d_kernel<<<512, 256, 0, stream>>>(input, b_d, out);
  // Stage B: the fused 68.7 GFLOP bilinear contraction
  stage_b<<<dim3(8, 64), 256, 0, stream>>>(x2, input, W_d, out);
}